// Round 6
// baseline (195.029 us; speedup 1.0000x reference)
//
#include <hip/hip_runtime.h>
#include <math.h>

#define BB 16
#define TQ 512
#define TK 1024
#define DD 512

typedef __bf16 bf16x8 __attribute__((ext_vector_type(8)));
typedef __bf16 bf16x4v __attribute__((ext_vector_type(4)));
typedef _Float16 f16x8 __attribute__((ext_vector_type(8)));
typedef _Float16 f16x4v __attribute__((ext_vector_type(4)));
typedef float f32x4 __attribute__((ext_vector_type(4)));

__device__ __forceinline__ unsigned short f16b(float x) {
    _Float16 h = (_Float16)x;
    return __builtin_bit_cast(unsigned short, h);
}

// async global(16B/lane) -> LDS (wave-uniform base + lane*16)
__device__ __forceinline__ void gload16(const void* g, void* l) {
    __builtin_amdgcn_global_load_lds(
        (const __attribute__((address_space(1))) unsigned int*)g,
        (__attribute__((address_space(3))) unsigned int*)l, 16, 0, 0);
}

// ============================================================================
// gemm16: NT GEMM on pre-converted fp16 operands, global_load_lds staging.
//  C[m][n] = sum_k A[m][k]*B[n][k]   OM=0: C fp32.  OM=2: fp16 -> D0.
// Tile TM x 128, 256 thr = 4 waves 2x2, wave tile (TM/2)x64, BK=64.
// LDS unpadded; 16B chunks XOR-swizzled within each 128B row.
// ============================================================================
template<int TM, int OM, bool BIAS, bool SCALE>
__global__ __launch_bounds__(256) void gemm16(
    const unsigned short* __restrict__ A0, const unsigned short* __restrict__ B0,
    float* __restrict__ C, unsigned short* __restrict__ D0,
    const float* __restrict__ bias, const float* __restrict__ scl,
    int N, int K, long sA, long sB, long sC)
{
    constexpr int WI = TM / 32;
    constexpr int IA = TM / 32;
    __shared__ unsigned short As0[TM * 64];
    __shared__ unsigned short Bs0[128 * 64];

    const int bz = blockIdx.z;
    const long oA = (long)bz * sA, oB = (long)bz * sB;
    const int m0 = blockIdx.y * TM;
    const int n0 = blockIdx.x * 128;
    const int tid = threadIdx.x, lane = tid & 63, wave = tid >> 6;
    const int wm0 = (wave >> 1) * (TM / 2);
    const int wn0 = (wave & 1) * 64;
    const int fm = lane & 15, fq = lane >> 4;

    f32x4 acc[WI][4];
    #pragma unroll
    for (int i = 0; i < WI; ++i)
        #pragma unroll
        for (int j = 0; j < 4; ++j) {
            f32x4 z = {0.f, 0.f, 0.f, 0.f};
            acc[i][j] = z;
        }

    for (int k0 = 0; k0 < K; k0 += 64) {
        #pragma unroll
        for (int t = 0; t < IA; ++t) {
            const int sb = (wave * IA + t) * 64;
            const int slot = sb + lane;
            const int row = slot >> 3;
            const int g = (slot & 7) ^ (row & 7);
            gload16(A0 + oA + (long)(m0 + row) * K + k0 + g * 8, &As0[sb * 8]);
        }
        #pragma unroll
        for (int t = 0; t < 4; ++t) {
            const int sb = (wave * 4 + t) * 64;
            const int slot = sb + lane;
            const int row = slot >> 3;
            const int g = (slot & 7) ^ (row & 7);
            gload16(B0 + oB + (long)(n0 + row) * K + k0 + g * 8, &Bs0[sb * 8]);
        }
        __syncthreads();

        #pragma unroll
        for (int s = 0; s < 2; ++s) {
            f16x8 fa[WI], fb[4];
            #pragma unroll
            for (int i = 0; i < WI; ++i) {
                const int row = wm0 + 16 * i + fm;
                const int slot = row * 8 + ((s * 4 + fq) ^ (row & 7));
                fa[i] = *(const f16x8*)&As0[slot * 8];
            }
            #pragma unroll
            for (int j = 0; j < 4; ++j) {
                const int row = wn0 + 16 * j + fm;
                const int slot = row * 8 + ((s * 4 + fq) ^ (row & 7));
                fb[j] = *(const f16x8*)&Bs0[slot * 8];
            }
            #pragma unroll
            for (int i = 0; i < WI; ++i)
                #pragma unroll
                for (int j = 0; j < 4; ++j)
                    acc[i][j] = __builtin_amdgcn_mfma_f32_16x16x32_f16(fa[i], fb[j], acc[i][j], 0, 0, 0);
        }
        __syncthreads();
    }

    const float sv = SCALE ? scl[0] : 1.0f;
    #pragma unroll
    for (int i = 0; i < WI; ++i) {
        #pragma unroll
        for (int j = 0; j < 4; ++j) {
            const int n = n0 + wn0 + 16 * j + fm;
            const float bv = BIAS ? bias[n] : 0.0f;
            #pragma unroll
            for (int r = 0; r < 4; ++r) {
                const int m = m0 + wm0 + 16 * i + fq * 4 + r;
                float v = acc[i][j][r] + bv;
                if (SCALE) v *= sv;
                const long o = (long)bz * sC + (long)m * N + n;
                if (OM == 0) C[o] = v;
                else         D0[o] = f16b(v);
            }
        }
    }
}

// ============================================================================
// fused_attn: scores + masked softmax + context, one block = 32 q-rows x full k.
// 4 waves; phase1 wave-split over key columns (wave covers cols Q*256+w*64..+63
// for each quarter Q); phase2 wave-split over d (w*128..+127).
// B operands read directly from global (no cross-wave reuse -> no LDS staging,
// no barriers in the K-loops; compiler pipelines loads with vmcnt).
// P (attn f16) transits LDS per key-quarter for the C-layout -> A-layout swap.
// ============================================================================
__global__ __launch_bounds__(256) void fused_attn(
    const unsigned short* __restrict__ aq16,  // [B*TQ][DD] f16
    const unsigned short* __restrict__ k16,   // [B][TK][DD] f16
    const unsigned short* __restrict__ kT,    // [B][DD][TK] f16
    float* __restrict__ attn,                 // [B][TQ][TK]
    float* __restrict__ ctx,                  // [B][TQ][DD]
    const int* __restrict__ lens, const float* __restrict__ scl)
{
    constexpr int LDP = 264;                  // P row stride (halves), +8 pad
    __shared__ unsigned short P[32 * LDP];    // 16,896 B
    __shared__ float redm[4][32];
    __shared__ float reds[4][32];

    const int b  = blockIdx.z;
    const int m0 = blockIdx.x * 32;
    const int tid = threadIdx.x, lane = tid & 63, wave = tid >> 6;
    const int fm = lane & 15, fq = lane >> 4;
    const int len = lens[b];
    const float sc = scl[0];

    // ---------------- Phase 1: S[m][key] = sum_d aq[m][d] * keys[key][d]
    f32x4 acc[2][16];
    #pragma unroll
    for (int i = 0; i < 2; ++i)
        #pragma unroll
        for (int jj = 0; jj < 16; ++jj) {
            f32x4 z = {0.f, 0.f, 0.f, 0.f};
            acc[i][jj] = z;
        }

    const unsigned short* Abase = aq16 + ((long)b * TQ + m0) * DD;
    const unsigned short* Bbase = k16 + (long)b * TK * DD;

    for (int dd = 0; dd < 8; ++dd) {          // d-chunks of 64
        f16x8 a[2][2];
        #pragma unroll
        for (int i = 0; i < 2; ++i)
            #pragma unroll
            for (int s = 0; s < 2; ++s)
                a[i][s] = *(const f16x8*)&Abase[(long)(16 * i + fm) * DD +
                                                dd * 64 + s * 32 + fq * 8];
        #pragma unroll
        for (int Q = 0; Q < 4; ++Q) {
            f16x8 bf[4][2];
            #pragma unroll
            for (int jq = 0; jq < 4; ++jq)
                #pragma unroll
                for (int s = 0; s < 2; ++s)
                    bf[jq][s] = *(const f16x8*)&Bbase[
                        (long)(Q * 256 + wave * 64 + jq * 16 + fm) * DD +
                        dd * 64 + s * 32 + fq * 8];
            #pragma unroll
            for (int i = 0; i < 2; ++i)
                #pragma unroll
                for (int jq = 0; jq < 4; ++jq)
                    #pragma unroll
                    for (int s = 0; s < 2; ++s)
                        acc[i][Q * 4 + jq] = __builtin_amdgcn_mfma_f32_16x16x32_f16(
                            a[i][s], bf[jq][s], acc[i][Q * 4 + jq], 0, 0, 0);
        }
    }

    // ---------------- masked softmax over full rows (in registers)
    // C/D layout: value (i,jj,r) is row = 16i + fq*4 + r,
    //             col = (jj>>2)*256 + wave*64 + (jj&3)*16 + fm
    float rmax[2][4];
    #pragma unroll
    for (int i = 0; i < 2; ++i)
        #pragma unroll
        for (int r = 0; r < 4; ++r) rmax[i][r] = -INFINITY;
    #pragma unroll
    for (int i = 0; i < 2; ++i)
        #pragma unroll
        for (int jj = 0; jj < 16; ++jj) {
            const int col = (jj >> 2) * 256 + wave * 64 + (jj & 3) * 16 + fm;
            const bool valid = col < len;
            #pragma unroll
            for (int r = 0; r < 4; ++r) {
                const float v = valid ? acc[i][jj][r] * sc : -INFINITY;
                acc[i][jj][r] = v;
                rmax[i][r] = fmaxf(rmax[i][r], v);
            }
        }
    #pragma unroll
    for (int off = 1; off < 16; off <<= 1)
        #pragma unroll
        for (int i = 0; i < 2; ++i)
            #pragma unroll
            for (int r = 0; r < 4; ++r)
                rmax[i][r] = fmaxf(rmax[i][r], __shfl_xor(rmax[i][r], off));
    if (fm == 0) {
        #pragma unroll
        for (int i = 0; i < 2; ++i)
            #pragma unroll
            for (int r = 0; r < 4; ++r)
                redm[wave][16 * i + fq * 4 + r] = rmax[i][r];
    }
    __syncthreads();
    #pragma unroll
    for (int i = 0; i < 2; ++i)
        #pragma unroll
        for (int r = 0; r < 4; ++r) {
            const int row = 16 * i + fq * 4 + r;
            rmax[i][r] = fmaxf(fmaxf(redm[0][row], redm[1][row]),
                               fmaxf(redm[2][row], redm[3][row]));
        }

    float rsum[2][4] = {};
    #pragma unroll
    for (int i = 0; i < 2; ++i)
        #pragma unroll
        for (int jj = 0; jj < 16; ++jj)
            #pragma unroll
            for (int r = 0; r < 4; ++r) {
                const float x = acc[i][jj][r];
                const float e = (x > -1e30f) ? __expf(x - rmax[i][r]) : 0.0f;
                acc[i][jj][r] = e;
                rsum[i][r] += e;
            }
    #pragma unroll
    for (int off = 1; off < 16; off <<= 1)
        #pragma unroll
        for (int i = 0; i < 2; ++i)
            #pragma unroll
            for (int r = 0; r < 4; ++r)
                rsum[i][r] += __shfl_xor(rsum[i][r], off);
    if (fm == 0) {
        #pragma unroll
        for (int i = 0; i < 2; ++i)
            #pragma unroll
            for (int r = 0; r < 4; ++r)
                reds[wave][16 * i + fq * 4 + r] = rsum[i][r];
    }
    __syncthreads();
    #pragma unroll
    for (int i = 0; i < 2; ++i)
        #pragma unroll
        for (int r = 0; r < 4; ++r) {
            const int row = 16 * i + fq * 4 + r;
            const float inv = 1.0f /
                (reds[0][row] + reds[1][row] + reds[2][row] + reds[3][row]);
            #pragma unroll
            for (int jj = 0; jj < 16; ++jj) acc[i][jj][r] *= inv;
        }

    // ---------------- write attn (fp32 output)
    {
        float* arow = attn + ((long)b * TQ + m0) * TK;
        #pragma unroll
        for (int i = 0; i < 2; ++i)
            #pragma unroll
            for (int jj = 0; jj < 16; ++jj) {
                const int col = (jj >> 2) * 256 + wave * 64 + (jj & 3) * 16 + fm;
                #pragma unroll
                for (int r = 0; r < 4; ++r) {
                    const int row = 16 * i + fq * 4 + r;
                    arow[(long)row * TK + col] = acc[i][jj][r];
                }
            }
    }

    // ---------------- Phase 2: O[m][d] = sum_key P[m][key] * kT[d][key]
    f32x4 acc2[2][8];
    #pragma unroll
    for (int i = 0; i < 2; ++i)
        #pragma unroll
        for (int j = 0; j < 8; ++j) {
            f32x4 z = {0.f, 0.f, 0.f, 0.f};
            acc2[i][j] = z;
        }

    const unsigned short* Tbase = kT + (long)b * DD * TK;
    for (int Q = 0; Q < 4; ++Q) {
        __syncthreads();                      // prior Q's P reads complete
        #pragma unroll
        for (int i = 0; i < 2; ++i)
            #pragma unroll
            for (int jq = 0; jq < 4; ++jq) {
                const int colq = wave * 64 + jq * 16 + fm;
                #pragma unroll
                for (int r = 0; r < 4; ++r) {
                    const int row = 16 * i + fq * 4 + r;
                    P[row * LDP + colq] = f16b(acc[i][Q * 4 + jq][r]);
                }
            }
        __syncthreads();
        for (int st = 0; st < 8; ++st) {      // 32 keys per step
            f16x8 a2[2], b2[8];
            #pragma unroll
            for (int i = 0; i < 2; ++i)
                a2[i] = *(const f16x8*)&P[(16 * i + fm) * LDP + st * 32 + fq * 8];
            #pragma unroll
            for (int j = 0; j < 8; ++j)
                b2[j] = *(const f16x8*)&Tbase[
                    (long)(wave * 128 + 16 * j + fm) * TK +
                    Q * 256 + st * 32 + fq * 8];
            #pragma unroll
            for (int i = 0; i < 2; ++i)
                #pragma unroll
                for (int j = 0; j < 8; ++j)
                    acc2[i][j] = __builtin_amdgcn_mfma_f32_16x16x32_f16(
                        a2[i], b2[j], acc2[i][j], 0, 0, 0);
        }
    }

    // ---------------- write ctx
    float* crow = ctx + ((long)b * TQ + m0) * DD;
    #pragma unroll
    for (int i = 0; i < 2; ++i)
        #pragma unroll
        for (int j = 0; j < 8; ++j) {
            const int col = wave * 128 + 16 * j + fm;
            #pragma unroll
            for (int r = 0; r < 4; ++r) {
                const int row = 16 * i + fq * 4 + r;
                crow[(long)row * DD + col] = acc2[i][j][r];
            }
        }
}

// query + Wq -> fp16 (float4 per thread)
__global__ __launch_bounds__(256) void cvt_qw_kernel(
    const float* __restrict__ q, const float* __restrict__ w,
    unsigned short* __restrict__ q16, unsigned short* __restrict__ w16,
    int nq4, int nw4)
{
    const int t = blockIdx.x * 256 + threadIdx.x;
    const float* s;
    unsigned short* d;
    if (t < nq4)            { s = q + (long)t * 4;         d = q16 + (long)t * 4; }
    else if (t < nq4 + nw4) { s = w + (long)(t - nq4) * 4; d = w16 + (long)(t - nq4) * 4; }
    else return;
    const float4 v = *(const float4*)s;
    f16x4v o = {(_Float16)v.x, (_Float16)v.y, (_Float16)v.z, (_Float16)v.w};
    *(f16x4v*)d = o;
}

// keys -> fp16 row-major [b][k][d] + fp16 transposed [b][d][k], 64x64 tiles
__global__ __launch_bounds__(256) void cvt_keys_kernel(
    const float* __restrict__ keys, unsigned short* __restrict__ k16,
    unsigned short* __restrict__ kT)
{
    __shared__ unsigned short T[64][72];
    const int b = blockIdx.z, kt = blockIdx.x, dt = blockIdx.y;
    const int tid = threadIdx.x;
    const float* src = keys + ((long)b * TK + (long)kt * 64) * DD + dt * 64;

    #pragma unroll
    for (int i = 0; i < 4; ++i) {
        const int slot = tid + i * 256;
        const int r  = slot >> 4;
        const int c4 = (slot & 15) * 4;
        const float4 v = *(const float4*)(src + (long)r * DD + c4);
        const unsigned short h0 = f16b(v.x), h1 = f16b(v.y),
                             h2 = f16b(v.z), h3 = f16b(v.w);
        *(ushort4*)&k16[((long)b * TK + kt * 64 + r) * DD + dt * 64 + c4] =
            make_ushort4(h0, h1, h2, h3);
        T[c4 + 0][r] = h0;
        T[c4 + 1][r] = h1;
        T[c4 + 2][r] = h2;
        T[c4 + 3][r] = h3;
    }
    __syncthreads();
    #pragma unroll
    for (int i = 0; i < 4; ++i) {
        const int slot = tid + i * 256;
        const int c  = slot >> 4;
        const int r4 = (slot & 15) * 4;
        const ushort4 o4 = *(const ushort4*)&T[c][r4];
        *(ushort4*)&kT[((long)b * DD + dt * 64 + c) * TK + kt * 64 + r4] = o4;
    }
}

// ============================================================================
// FALLBACK PATH: fp32-input MFMA GEMM with in-loop conversion (round-3 proven).
// ============================================================================
template<int TM, bool SPLIT, bool BT, bool BIAS, bool SCALE>
__global__ __launch_bounds__(256) void mfma_gemm(
    const float* __restrict__ A, const float* __restrict__ Bm,
    float* __restrict__ C, const float* __restrict__ bias,
    const float* __restrict__ scl,
    int N, int K, long sA, long sB, long sC)
{
    constexpr int WI  = TM / 32;
    constexpr int LDT = 40;
    __shared__ unsigned short As_hi[TM * LDT];
    __shared__ unsigned short Bs_hi[128 * LDT];
    __shared__ unsigned short As_lo[SPLIT ? TM * LDT : 8];
    __shared__ unsigned short Bs_lo[SPLIT ? 128 * LDT : 8];

    const int bz = blockIdx.z;
    A  += (long)bz * sA;
    Bm += (long)bz * sB;
    C  += (long)bz * sC;

    const int m0 = blockIdx.y * TM;
    const int n0 = blockIdx.x * 128;
    const int tid  = threadIdx.x;
    const int lane = tid & 63;
    const int wave = tid >> 6;
    const int wm0 = (wave >> 1) * (TM / 2);
    const int wn0 = (wave & 1) * 64;
    const int fm = lane & 15;
    const int fq = lane >> 4;

    f32x4 acc[WI][4];
    #pragma unroll
    for (int i = 0; i < WI; ++i)
        #pragma unroll
        for (int j = 0; j < 4; ++j) {
            f32x4 z = {0.f, 0.f, 0.f, 0.f};
            acc[i][j] = z;
        }

    for (int k0 = 0; k0 < K; k0 += 32) {
        #pragma unroll
        for (int i = 0; i < WI; ++i) {
            const int s   = tid + i * 256;
            const int row = s >> 3;
            const int c4  = (s & 7) << 2;
            const float4 v = *(const float4*)(A + (long)(m0 + row) * K + k0 + c4);
            if (SPLIT) {
                const __bf16 h0 = (__bf16)v.x, h1 = (__bf16)v.y,
                             h2 = (__bf16)v.z, h3 = (__bf16)v.w;
                bf16x4v hv = {h0, h1, h2, h3};
                *(bf16x4v*)&As_hi[row * LDT + c4] = hv;
                bf16x4v lv = {(__bf16)(v.x - (float)h0), (__bf16)(v.y - (float)h1),
                              (__bf16)(v.z - (float)h2), (__bf16)(v.w - (float)h3)};
                *(bf16x4v*)&As_lo[row * LDT + c4] = lv;
            } else {
                f16x4v hv = {(_Float16)v.x, (_Float16)v.y, (_Float16)v.z, (_Float16)v.w};
                *(f16x4v*)&As_hi[row * LDT + c4] = hv;
            }
        }
        if (BT) {
            #pragma unroll
            for (int i = 0; i < 4; ++i) {
                const int s   = tid + i * 256;
                const int row = s >> 3;
                const int c4  = (s & 7) << 2;
                const float4 v = *(const float4*)(Bm + (long)(n0 + row) * K + k0 + c4);
                if (SPLIT) {
                    const __bf16 h0 = (__bf16)v.x, h1 = (__bf16)v.y,
                                 h2 = (__bf16)v.z, h3 = (__bf16)v.w;
                    bf16x4v hv = {h0, h1, h2, h3};
                    *(bf16x4v*)&Bs_hi[row * LDT + c4] = hv;
                    bf16x4v lv = {(__bf16)(v.x - (float)h0), (__bf16)(v.y - (float)h1),
                                  (__bf16)(v.z - (float)h2), (__bf16)(v.w - (float)h3)};
                    *(bf16x4v*)&Bs_lo[row * LDT + c4] = lv;
                } else {
                    f16x4v hv = {(_Float16)v.x, (_Float16)v.y, (_Float16)v.z, (_Float16)v.w};
                    *(f16x4v*)&Bs_hi[row * LDT + c4] = hv;
                }
            }
        } else {
            const int n  = tid & 127;
            const int kh2 = tid >> 7;
            const float* src = Bm + (long)(k0 + kh2 * 16) * N + n0 + n;
            float xs[16];
            #pragma unroll
            for (int j2 = 0; j2 < 16; ++j2) xs[j2] = src[(long)j2 * N];
            #pragma unroll
            for (int w2 = 0; w2 < 4; ++w2) {
                if (SPLIT) {
                    const __bf16 h0 = (__bf16)xs[w2*4+0], h1 = (__bf16)xs[w2*4+1],
                                 h2 = (__bf16)xs[w2*4+2], h3 = (__bf16)xs[w2*4+3];
                    bf16x4v hv = {h0, h1, h2, h3};
                    *(bf16x4v*)&Bs_hi[n * LDT + kh2 * 16 + w2 * 4] = hv;
                    bf16x4v lv = {(__bf16)(xs[w2*4+0] - (float)h0),
                                  (__bf16)(xs[w2*4+1] - (float)h1),
                                  (__bf16)(xs[w2*4+2] - (float)h2),
                                  (__bf16)(xs[w2*4+3] - (float)h3)};
                    *(bf16x4v*)&Bs_lo[n * LDT + kh2 * 16 + w2 * 4] = lv;
                } else {
                    f16x4v hv = {(_Float16)xs[w2*4+0], (_Float16)xs[w2*4+1],
                                 (_Float16)xs[w2*4+2], (_Float16)xs[w2*4+3]};
                    *(f16x4v*)&Bs_hi[n * LDT + kh2 * 16 + w2 * 4] = hv;
                }
            }
        }
        __syncthreads();

        if (SPLIT) {
            bf16x8 ah[WI], al[WI], bh[4], bl[4];
            #pragma unroll
            for (int i = 0; i < WI; ++i) {
                const int ra = (wm0 + 16 * i + fm) * LDT + fq * 8;
                ah[i] = *(const bf16x8*)&As_hi[ra];
                al[i] = *(const bf16x8*)&As_lo[ra];
            }
            #pragma unroll
            for (int j = 0; j < 4; ++j) {
                const int rb = (wn0 + 16 * j + fm) * LDT + fq * 8;
                bh[j] = *(const bf16x8*)&Bs_hi[rb];
                bl[j] = *(const bf16x8*)&Bs_lo[rb];
            }
            #pragma unroll
            for (int i = 0; i < WI; ++i)
                #pragma unroll
                for (int j = 0; j < 4; ++j) {
                    acc[i][j] = __builtin_amdgcn_mfma_f32_16x16x32_bf16(ah[i], bh[j], acc[i][j], 0, 0, 0);
                    acc[i][j] = __builtin_amdgcn_mfma_f32_16x16x32_bf16(ah[i], bl[j], acc[i][j], 0, 0, 0);
                    acc[i][j] = __builtin_amdgcn_mfma_f32_16x16x32_bf16(al[i], bh[j], acc[i][j], 0, 0, 0);
                }
        } else {
            f16x8 fa[WI], fb[4];
            #pragma unroll
            for (int i = 0; i < WI; ++i)
                fa[i] = *(const f16x8*)&As_hi[(wm0 + 16 * i + fm) * LDT + fq * 8];
            #pragma unroll
            for (int j = 0; j < 4; ++j)
                fb[j] = *(const f16x8*)&Bs_hi[(wn0 + 16 * j + fm) * LDT + fq * 8];
            #pragma unroll
            for (int i = 0; i < WI; ++i)
                #pragma unroll
                for (int j = 0; j < 4; ++j)
                    acc[i][j] = __builtin_amdgcn_mfma_f32_16x16x32_f16(fa[i], fb[j], acc[i][j], 0, 0, 0);
        }
        __syncthreads();
    }

    const float s = SCALE ? scl[0] : 1.0f;
    #pragma unroll
    for (int i = 0; i < WI; ++i) {
        #pragma unroll
        for (int j = 0; j < 4; ++j) {
            const int n = n0 + wn0 + 16 * j + fm;
            float bv = BIAS ? bias[n] : 0.0f;
            #pragma unroll
            for (int r = 0; r < 4; ++r) {
                const int m = m0 + wm0 + 16 * i + fq * 4 + r;
                float v = acc[i][j][r] + bv;
                if (SCALE) v *= s;
                C[(long)m * N + n] = v;
            }
        }
    }
}

// Masked softmax (fallback path), one block per (b,q) row.
__global__ __launch_bounds__(256) void softmax_kernel(
    float* __restrict__ attn, const int* __restrict__ lens)
{
    const int row = blockIdx.x;
    const int b   = row >> 9;
    const int len = lens[b];
    float* p = attn + (long)row * TK;

    const int tid  = threadIdx.x;
    const int lane = tid & 63;
    const int wave = tid >> 6;
    const int k0   = tid * 4;

    const float4 v = *(const float4*)(p + k0);
    float x[4] = {v.x, v.y, v.z, v.w};
    float mx = -INFINITY;
    #pragma unroll
    for (int i = 0; i < 4; ++i) {
        if (k0 + i < len) mx = fmaxf(mx, x[i]);
        else x[i] = -INFINITY;
    }
    #pragma unroll
    for (int off = 32; off; off >>= 1) mx = fmaxf(mx, __shfl_xor(mx, off, 64));

    __shared__ float red[8];
    if (lane == 0) red[wave] = mx;
    __syncthreads();
    mx = fmaxf(fmaxf(red[0], red[1]), fmaxf(red[2], red[3]));

    float e[4];
    float sum = 0.0f;
    #pragma unroll
    for (int i = 0; i < 4; ++i) {
        e[i] = (x[i] > -INFINITY) ? __expf(x[i] - mx) : 0.0f;
        sum += e[i];
    }
    #pragma unroll
    for (int off = 32; off; off >>= 1) sum += __shfl_xor(sum, off, 64);
    if (lane == 0) red[4 + wave] = sum;
    __syncthreads();
    sum = red[4] + red[5] + red[6] + red[7];

    const float inv = 1.0f / sum;
    float4 o = {e[0] * inv, e[1] * inv, e[2] * inv, e[3] * inv};
    *(float4*)(p + k0) = o;
}

extern "C" void kernel_launch(void* const* d_in, const int* in_sizes, int n_in,
                              void* d_out, int out_size, void* d_ws, size_t ws_size,
                              hipStream_t stream) {
    (void)in_sizes; (void)n_in; (void)out_size;

    const float* query = (const float*)d_in[0];
    const float* keys  = (const float*)d_in[1];
    const int*   lens  = (const int*)d_in[2];
    const float* Wq    = (const float*)d_in[3];
    const float* bq    = (const float*)d_in[4];
    const float* scale = (const float*)d_in[5];

    float* out  = (float*)d_out;
    float* ctx  = out;                               // B*TQ*D
    float* attn = out + (size_t)BB * TQ * DD;        // B*TQ*TK

    const size_t NQ  = (size_t)BB * TQ * DD;   // 4,194,304
    const size_t NW  = (size_t)DD * DD;        //   262,144
    const size_t NK  = (size_t)BB * TK * DD;   // 8,388,608
    const size_t REQ = (2 * NQ + NW + 2 * NK) * 2;   // ~51 MB

    if (ws_size >= REQ) {
        unsigned short* w = (unsigned short*)d_ws;
        unsigned short* q16  = w;               w += NQ;
        unsigned short* w16  = w;               w += NW;
        unsigned short* aq16 = w;               w += NQ;
        unsigned short* k16  = w;               w += NK;
        unsigned short* kT   = w;

        // 0a) query+Wq -> fp16
        const int nq4 = (int)(NQ / 4), nw4 = (int)(NW / 4);
        cvt_qw_kernel<<<(nq4 + nw4 + 255) / 256, 256, 0, stream>>>(
            query, Wq, q16, w16, nq4, nw4);
        // 0b) keys -> fp16 + fp16 transposed
        cvt_keys_kernel<<<dim3(TK / 64, DD / 64, BB), 256, 0, stream>>>(
            keys, k16, kT);

        // 1) aq16 = f16gemm(query,Wq) + bq   M=8192 N=512 K=512
        gemm16<64, 2, true, false>
            <<<dim3(DD / 128, (BB * TQ) / 64, 1), 256, 0, stream>>>(
            q16, w16, nullptr, aq16, bq, nullptr, DD, DD, 0, 0, 0);

        // 2) fused scores + masked softmax + context
        fused_attn<<<dim3(TQ / 32, 1, BB), 256, 0, stream>>>(
            aq16, k16, kT, attn, ctx, lens, scale);
    } else {
        // fallback: round-3 path (in-loop conversion)
        float* aq = ctx;
        mfma_gemm<64, false, true, true, false>
            <<<dim3(DD / 128, (BB * TQ) / 64, 1), 256, 0, stream>>>(
            query, Wq, aq, bq, nullptr, DD, DD, 0, 0, 0);
        mfma_gemm<128, true, true, false, true>
            <<<dim3(TK / 128, TQ / 128, BB), 256, 0, stream>>>(
            aq, keys, attn, nullptr, scale, TK, DD,
            (long)TQ * DD, (long)TK * DD, (long)TQ * TK);
        softmax_kernel<<<BB * TQ, 256, 0, stream>>>(attn, lens);
        mfma_gemm<64, false, false, false, false>
            <<<dim3(DD / 128, TQ / 64, BB), 256, 0, stream>>>(
            attn, keys, ctx, nullptr, nullptr, DD, TK,
            (long)TQ * TK, (long)TK * DD, (long)TQ * DD);
    }
}